// Round 3
// baseline (229.446 us; speedup 1.0000x reference)
//
#include <hip/hip_runtime.h>
#include <hip/hip_bf16.h>

#define HID    128     // hidden width per half
#define K256   256
#define TILE_M 64      // rows per block
#define TILE_E 64

typedef __attribute__((ext_vector_type(8))) short bf16x8;
typedef __attribute__((ext_vector_type(4))) float floatx4;

__device__ __forceinline__ unsigned short f2bf(float f) {
  // native convert: compiler emits v_cvt_pk_bf16_f32 for pairs (RNE)
  __hip_bfloat16 b = __float2bfloat16(f);
  return __builtin_bit_cast(unsigned short, b);
}
__device__ __forceinline__ float bf2f(short s) {
  union { unsigned u; float f; } v; v.u = ((unsigned)(unsigned short)s) << 16;
  return v.f;
}
__device__ __forceinline__ bf16x8 pack8(float4 a, float4 b) {
  bf16x8 r;
  r[0] = (short)f2bf(a.x); r[1] = (short)f2bf(a.y);
  r[2] = (short)f2bf(a.z); r[3] = (short)f2bf(a.w);
  r[4] = (short)f2bf(b.x); r[5] = (short)f2bf(b.y);
  r[6] = (short)f2bf(b.z); r[7] = (short)f2bf(b.w);
  return r;
}
__device__ __forceinline__ float i8at(uint2 q, int j) {
  unsigned w = (j < 4) ? q.x : q.y;
  return (float)((int)(signed char)(w >> (8 * (j & 3))));
}

// ---------------- Phase 1: H = z * W1halfT  (M x 128, K=128) ----------------
// Latency-bound before (3 barriers + LDS round-trip for A + manual bf16 cvt).
// Now: each wave loads its MFMA A-fragments DIRECTLY from global z (K=128 is
// 4 fragment loads; 4x L2 amplification absorbed by L1/L2), MFMA starts with
// no barrier. Epilogue: per-row amax from fp32 acc via shfl + 1KB LDS combine,
// conflict-free XOR C-transpose, int8 quantized store. ONE __syncthreads total.
__global__ __launch_bounds__(256, 4)
void node_proj(const float* __restrict__ zs, const float* __restrict__ zd,
               const float* __restrict__ W1,
               unsigned char* __restrict__ Hqs, unsigned char* __restrict__ Hqd,
               float* __restrict__ Ss, float* __restrict__ Sd,
               int M)
{
  __shared__ unsigned short Ct[TILE_M * HID];  // 16 KiB C transpose
  __shared__ float pmax[4][TILE_M];            // 1 KiB per-wave row partial amax

  const int which = blockIdx.y;
  const float* __restrict__ z = which ? zd : zs;
  unsigned char* __restrict__ Hq = which ? Hqd : Hqs;
  float* __restrict__ S = which ? Sd : Ss;
  const int koff = which * HID;

  const int tid  = threadIdx.x;
  const int lane = tid & 63;
  const int w    = tid >> 6;
  const int nlo  = lane & 15;
  const int quad = lane >> 4;
  const int r0   = blockIdx.x * TILE_M;

  // ---- W1 B-fragments (L2-hot, 32 KB/block-half) ----
  bf16x8 bfr[2][4];
  const int nb = w * 32;
#pragma unroll
  for (int nt = 0; nt < 2; ++nt) {
    const int n = nb + nt * 16 + nlo;
#pragma unroll
    for (int kt = 0; kt < 4; ++kt) {
      const float* p = W1 + (size_t)n * K256 + koff + kt * 32 + quad * 8;
      bfr[nt][kt] = pack8(*(const float4*)p, *(const float4*)(p + 4));
    }
  }

  // ---- MFMA with A-fragments straight from global ----
  floatx4 acc[4][2];
#pragma unroll
  for (int mt = 0; mt < 4; ++mt)
#pragma unroll
    for (int nt = 0; nt < 2; ++nt)
      acc[mt][nt] = (floatx4){0.f, 0.f, 0.f, 0.f};

#pragma unroll
  for (int kt = 0; kt < 4; ++kt) {
    bf16x8 a[4];
#pragma unroll
    for (int mt = 0; mt < 4; ++mt) {
      int gr = r0 + mt * 16 + nlo;
      gr = (gr < M) ? gr : (M - 1);        // clamped; padded rows excluded at store
      const float* p = z + (size_t)gr * HID + kt * 32 + quad * 8;
      a[mt] = pack8(*(const float4*)p, *(const float4*)(p + 4));
    }
#pragma unroll
    for (int mt = 0; mt < 4; ++mt)
#pragma unroll
      for (int nt = 0; nt < 2; ++nt)
        acc[mt][nt] = __builtin_amdgcn_mfma_f32_16x16x32_bf16(
            a[mt], bfr[nt][kt], acc[mt][nt], 0, 0, 0);
  }

  // ---- per-wave row partial amax from fp32 acc (shfl over the 16 n-lanes) ----
#pragma unroll
  for (int mt = 0; mt < 4; ++mt) {
#pragma unroll
    for (int r = 0; r < 4; ++r) {
      float pm = fmaxf(__builtin_fabsf(acc[mt][0][r]), __builtin_fabsf(acc[mt][1][r]));
      pm = fmaxf(pm, __shfl_xor(pm, 1));
      pm = fmaxf(pm, __shfl_xor(pm, 2));
      pm = fmaxf(pm, __shfl_xor(pm, 4));
      pm = fmaxf(pm, __shfl_xor(pm, 8));
      if (nlo == 0) pmax[w][mt * 16 + quad * 4 + r] = pm;
    }
  }

  // ---- C -> LDS (bf16, conflict-free XOR-chunk swizzle) ----
#pragma unroll
  for (int mt = 0; mt < 4; ++mt) {
#pragma unroll
    for (int r = 0; r < 4; ++r) {
      const int rowl = mt * 16 + quad * 4 + r;
#pragma unroll
      for (int nt = 0; nt < 2; ++nt) {
        const int col = nb + nt * 16 + nlo;
        const int sw  = ((col >> 3) ^ (rowl & 15)) * 8 + (col & 7);
        Ct[rowl * HID + sw] = f2bf(acc[mt][nt][r]);
      }
    }
  }
  __syncthreads();

  // ---- int8 quantized store: per-row amax scale, 8 B/thread ----
#pragma unroll
  for (int i = 0; i < 4; ++i) {
    const int c   = tid + i * 256;
    const int row = c >> 4;
    const int c16 = c & 15;
    const int gr  = r0 + row;
    bf16x8 v = *(const bf16x8*)(Ct + row * HID + ((c16 ^ (row & 15)) * 8));
    const float m = fmaxf(fmaxf(pmax[0][row], pmax[1][row]),
                          fmaxf(pmax[2][row], pmax[3][row]));
    const float inv = (m > 0.f) ? 127.f / m : 0.f;
    unsigned lo = 0, hi = 0;
#pragma unroll
    for (int j = 0; j < 4; ++j) {
      const int q = (int)rintf(bf2f(v[j]) * inv);
      lo |= ((unsigned)(q & 0xff)) << (8 * j);
    }
#pragma unroll
    for (int j = 0; j < 4; ++j) {
      const int q = (int)rintf(bf2f(v[4 + j]) * inv);
      hi |= ((unsigned)(q & 0xff)) << (8 * j);
    }
    if (gr < M) {
      *(uint2*)(Hq + (size_t)gr * HID + c16 * 8) = make_uint2(lo, hi);
      if (c16 == 0) S[gr] = m * (1.f / 127.f);
    }
  }
}

// ---------------- Phase 2: out[e] = W2 . relu(dq(Hqs[row]) + dq(Hqd[col]) + b1) + b2 ----
// int8 rows: 128 B gather per side + broadcast scalar scale (L2-resident).
__global__ __launch_bounds__(256, 8)
void edge_eval(const unsigned char* __restrict__ Hqs,
               const unsigned char* __restrict__ Hqd,
               const float* __restrict__ Ss, const float* __restrict__ Sd,
               const int* __restrict__ eidx,
               const float* __restrict__ b1, const float* __restrict__ W2,
               const float* __restrict__ b2,
               float* __restrict__ out, int E)
{
  const int tid = threadIdx.x;
  const int l16 = tid & 15;
  const int ebase = blockIdx.x * 64 + (tid >> 4) * 4;

  int rows[4], cols[4];
#pragma unroll
  for (int u = 0; u < 4; ++u) {
    const int e = ebase + u;
    const bool ok = e < E;
    rows[u] = ok ? eidx[e] : 0;
    cols[u] = ok ? eidx[E + e] : 0;
  }

  uint2 qs[4], qd[4];
  float ss[4], sd[4];
#pragma unroll
  for (int u = 0; u < 4; ++u)
    qs[u] = *(const uint2*)(Hqs + (size_t)rows[u] * HID + l16 * 8);
#pragma unroll
  for (int u = 0; u < 4; ++u)
    qd[u] = *(const uint2*)(Hqd + (size_t)cols[u] * HID + l16 * 8);
#pragma unroll
  for (int u = 0; u < 4; ++u) ss[u] = Ss[rows[u]];
#pragma unroll
  for (int u = 0; u < 4; ++u) sd[u] = Sd[cols[u]];

  float4 b1a = *(const float4*)(b1 + l16 * 8);
  float4 b1b = *(const float4*)(b1 + l16 * 8 + 4);
  float4 w2a = *(const float4*)(W2 + l16 * 8);
  float4 w2b = *(const float4*)(W2 + l16 * 8 + 4);
  const float b1v[8] = {b1a.x, b1a.y, b1a.z, b1a.w, b1b.x, b1b.y, b1b.z, b1b.w};
  const float w2v[8] = {w2a.x, w2a.y, w2a.z, w2a.w, w2b.x, w2b.y, w2b.z, w2b.w};
  const float bias2 = b2[0];

  float v[4];
#pragma unroll
  for (int u = 0; u < 4; ++u) {
    float s = 0.f;
#pragma unroll
    for (int j = 0; j < 8; ++j) {
      float x = fmaf(i8at(qs[u], j), ss[u], fmaf(i8at(qd[u], j), sd[u], b1v[j]));
      x = fmaxf(x, 0.f);
      s = fmaf(x, w2v[j], s);
    }
    s += __shfl_xor(s, 1);
    s += __shfl_xor(s, 2);
    s += __shfl_xor(s, 4);
    s += __shfl_xor(s, 8);
    v[u] = s;
  }
  if (l16 < 4) {
    const int e = ebase + l16;
    const float vo = (l16 == 0) ? v[0] : (l16 == 1) ? v[1] : (l16 == 2) ? v[2] : v[3];
    if (e < E) out[e] = vo + bias2;
  }
}

// ---------------- Fallback (ws too small): fused kernel, fp32 direct ----------------
__global__ __launch_bounds__(256, 4)
void edge_decoder_f32(const float* __restrict__ zsrc_f, const float* __restrict__ zdst_f,
                      const int* __restrict__ eidx,
                      const float* __restrict__ W1f,
                      const float* __restrict__ b1, const float* __restrict__ W2,
                      const float* __restrict__ b2,
                      float* __restrict__ out, int E)
{
  __shared__ unsigned short Zt[TILE_E * K256];
  __shared__ int   idxs[2 * TILE_E];
  __shared__ float part[4 * TILE_E];

  const int tid  = threadIdx.x;
  const int lane = tid & 63;
  const int nh   = tid >> 6;
  const int nlo  = lane & 15;
  const int quad = lane >> 4;
  const int e0   = blockIdx.x * TILE_E;

  if (tid < 2 * TILE_E) {
    const int ee = e0 + (tid & 63);
    idxs[tid] = (ee < E) ? eidx[(tid >> 6) * E + ee] : 0;
  }
  __syncthreads();

#pragma unroll
  for (int it = 0; it < 8; ++it) {
    const int c   = tid + it * 256;
    const int row = c >> 4;
    const int l16 = c & 15;
    const int e   = row >> 1;
    const int h   = row & 1;
    const int node = idxs[h * TILE_E + e];
    const int cs  = ((h << 4) | l16) ^ (e & 31);
    const float* p = (h ? zdst_f : zsrc_f) + (size_t)node * HID + l16 * 8;
    bf16x8 v = pack8(*(const float4*)p, *(const float4*)(p + 4));
    *(bf16x8*)(Zt + e * K256 + cs * 8) = v;
  }
  __syncthreads();

  bf16x8 w1f[2][8];
  const int nb = nh * 32;
#pragma unroll
  for (int nt = 0; nt < 2; ++nt) {
    const int n = nb + nt * 16 + nlo;
#pragma unroll
    for (int kt = 0; kt < 8; ++kt) {
      const float* p = W1f + (size_t)n * K256 + kt * 32 + quad * 8;
      w1f[nt][kt] = pack8(*(const float4*)p, *(const float4*)(p + 4));
    }
  }

  floatx4 acc[4][2];
#pragma unroll
  for (int mt = 0; mt < 4; ++mt)
#pragma unroll
    for (int nt = 0; nt < 2; ++nt)
      acc[mt][nt] = (floatx4){0.f, 0.f, 0.f, 0.f};

#pragma unroll
  for (int kt = 0; kt < 8; ++kt) {
    bf16x8 a[4];
#pragma unroll
    for (int mt = 0; mt < 4; ++mt) {
      const int m  = mt * 16 + nlo;
      const int cs = (kt * 4 + quad) ^ (m & 31);
      a[mt] = *(const bf16x8*)(Zt + m * K256 + cs * 8);
    }
#pragma unroll
    for (int mt = 0; mt < 4; ++mt)
#pragma unroll
      for (int nt = 0; nt < 2; ++nt)
        acc[mt][nt] = __builtin_amdgcn_mfma_f32_16x16x32_bf16(
            a[mt], w1f[nt][kt], acc[mt][nt], 0, 0, 0);
  }

  float b1v[2], w2v[2];
#pragma unroll
  for (int nt = 0; nt < 2; ++nt) {
    const int n = nb + nt * 16 + nlo;
    b1v[nt] = b1[n];
    w2v[nt] = W2[n];
  }
#pragma unroll
  for (int mt = 0; mt < 4; ++mt) {
#pragma unroll
    for (int r = 0; r < 4; ++r) {
      float v = 0.f;
#pragma unroll
      for (int nt = 0; nt < 2; ++nt) {
        float x = acc[mt][nt][r] + b1v[nt];
        x = fmaxf(x, 0.f);
        v = fmaf(x, w2v[nt], v);
      }
      v += __shfl_xor(v, 1);
      v += __shfl_xor(v, 2);
      v += __shfl_xor(v, 4);
      v += __shfl_xor(v, 8);
      if (nlo == 0)
        part[nh * TILE_E + mt * 16 + quad * 4 + r] = v;
    }
  }
  __syncthreads();
  if (tid < TILE_E && e0 + tid < E)
    out[e0 + tid] = part[tid] + part[TILE_E + tid] + part[2 * TILE_E + tid]
                  + part[3 * TILE_E + tid] + b2[0];
}

extern "C" void kernel_launch(void* const* d_in, const int* in_sizes, int n_in,
                              void* d_out, int out_size, void* d_ws, size_t ws_size,
                              hipStream_t stream) {
  const float* z_src = (const float*)d_in[0];
  const float* z_dst = (const float*)d_in[1];
  const int*   eidx  = (const int*)d_in[2];
  const float* W1    = (const float*)d_in[3];
  const float* b1    = (const float*)d_in[4];
  const float* W2    = (const float*)d_in[5];
  const float* b2    = (const float*)d_in[6];
  float* out = (float*)d_out;

  const int NH = in_sizes[0];        // 12,800,000 = M * 128
  const int M  = NH / HID;           // 100,000
  const int E  = in_sizes[2] / 2;    // 1,000,000

  const size_t rowBytes = (size_t)M * HID;                    // int8 per side
  const size_t need = rowBytes * 2 + 2 * (size_t)M * sizeof(float);
  if (ws_size >= need) {
    unsigned char* Hqs = (unsigned char*)d_ws;
    unsigned char* Hqd = Hqs + rowBytes;
    float* Ss = (float*)(Hqd + rowBytes);
    float* Sd = Ss + M;
    const int nMt = (M + TILE_M - 1) / TILE_M;   // 1563
    node_proj<<<dim3(nMt, 2), 256, 0, stream>>>(z_src, z_dst, W1, Hqs, Hqd, Ss, Sd, M);
    edge_eval<<<(E + 63) / 64, 256, 0, stream>>>(Hqs, Hqd, Ss, Sd, eidx, b1, W2, b2, out, E);
  } else {
    const int nblk = (E + TILE_E - 1) / TILE_E;
    edge_decoder_f32<<<nblk, 256, 0, stream>>>(z_src, z_dst, eidx, W1, b1, W2, b2, out, E);
  }
}

// Round 4
// 191.017 us; speedup vs baseline: 1.2012x; 1.2012x over previous
//
#include <hip/hip_runtime.h>
#include <hip/hip_bf16.h>

#define HID    128     // hidden width per half
#define K256   256
#define TILE_M 64      // rows per block (SUB=1: max grid parallelism; W1 is L2-hot)
#define TILE_E 64

typedef __attribute__((ext_vector_type(8))) short bf16x8;
typedef __attribute__((ext_vector_type(4))) float floatx4;

__device__ __forceinline__ unsigned short f2bf(float f) {
  // native convert: compiler pairs these into v_cvt_pk_bf16_f32 (RNE)
  __hip_bfloat16 b = __float2bfloat16(f);
  return __builtin_bit_cast(unsigned short, b);
}
__device__ __forceinline__ float bf2f(short s) {
  union { unsigned u; float f; } v; v.u = ((unsigned)(unsigned short)s) << 16;
  return v.f;
}
__device__ __forceinline__ bf16x8 pack8(float4 a, float4 b) {
  bf16x8 r;
  r[0] = (short)f2bf(a.x); r[1] = (short)f2bf(a.y);
  r[2] = (short)f2bf(a.z); r[3] = (short)f2bf(a.w);
  r[4] = (short)f2bf(b.x); r[5] = (short)f2bf(b.y);
  r[6] = (short)f2bf(b.z); r[7] = (short)f2bf(b.w);
  return r;
}
__device__ __forceinline__ float i8at(uint2 q, int j) {
  unsigned w = (j < 4) ? q.x : q.y;
  return (float)((int)(signed char)(w >> (8 * (j & 3))));
}

// ---------------- Phase 1: H = z * W1halfT  (M x 128, K=128) ----------------
// R1 structure (best measured): coalesced LDS-staged A, one 64-row tile per
// block, grid 1563x2. Sole change vs R1: native v_cvt_pk bf16 conversion
// (was ~640 manual-RNE VALU ops/thread -> ~64 cvt_pk; VALU chain is on the
// latency-bound critical path). Epilogue quantizes rows to int8, per-row amax.
__global__ __launch_bounds__(256, 4)
void node_proj(const float* __restrict__ zs, const float* __restrict__ zd,
               const float* __restrict__ W1,
               unsigned char* __restrict__ Hqs, unsigned char* __restrict__ Hqd,
               float* __restrict__ Ss, float* __restrict__ Sd,
               int M)
{
  __shared__ unsigned short At[TILE_M * HID];  // 16 KiB, reused: A-tile then C-tile

  const int which = blockIdx.y;
  const float* __restrict__ z = which ? zd : zs;
  unsigned char* __restrict__ Hq = which ? Hqd : Hqs;
  float* __restrict__ S = which ? Sd : Ss;
  const int koff = which * HID;

  const int tid  = threadIdx.x;
  const int lane = tid & 63;
  const int w    = tid >> 6;
  const int nlo  = lane & 15;
  const int quad = lane >> 4;
  const int r0   = blockIdx.x * TILE_M;

  // ---- stage A-tile first (z is the HBM-latency path), fp32 -> bf16, XOR swizzle ----
#pragma unroll
  for (int i = 0; i < 4; ++i) {
    const int c   = tid + i * 256;
    const int row = c >> 4;
    const int c16 = c & 15;
    const int gr  = r0 + row;
    bf16x8 v = (bf16x8){0,0,0,0,0,0,0,0};
    if (gr < M) {
      const float* p = z + (size_t)gr * HID + c16 * 8;
      v = pack8(*(const float4*)p, *(const float4*)(p + 4));
    }
    *(bf16x8*)(At + row * HID + ((c16 ^ (row & 15)) * 8)) = v;
  }

  // ---- W1 B-fragments (L2-hot, 32 KB/block-half) ----
  bf16x8 bfr[2][4];
  const int nb = w * 32;
#pragma unroll
  for (int nt = 0; nt < 2; ++nt) {
    const int n = nb + nt * 16 + nlo;
#pragma unroll
    for (int kt = 0; kt < 4; ++kt) {
      const float* p = W1 + (size_t)n * K256 + koff + kt * 32 + quad * 8;
      bfr[nt][kt] = pack8(*(const float4*)p, *(const float4*)(p + 4));
    }
  }
  __syncthreads();

  // ---- MFMA ----
  floatx4 acc[4][2];
#pragma unroll
  for (int mt = 0; mt < 4; ++mt)
#pragma unroll
    for (int nt = 0; nt < 2; ++nt)
      acc[mt][nt] = (floatx4){0.f, 0.f, 0.f, 0.f};

#pragma unroll
  for (int kt = 0; kt < 4; ++kt) {
    bf16x8 a[4];
#pragma unroll
    for (int mt = 0; mt < 4; ++mt) {
      const int m  = mt * 16 + nlo;
      const int cs = (kt * 4 + quad) ^ nlo;
      a[mt] = *(const bf16x8*)(At + m * HID + cs * 8);
    }
#pragma unroll
    for (int mt = 0; mt < 4; ++mt)
#pragma unroll
      for (int nt = 0; nt < 2; ++nt)
        acc[mt][nt] = __builtin_amdgcn_mfma_f32_16x16x32_bf16(
            a[mt], bfr[nt][kt], acc[mt][nt], 0, 0, 0);
  }

  __syncthreads();                          // all A reads done -> reuse At for C
  // ---- C -> LDS (bf16, same XOR-chunk swizzle) ----
#pragma unroll
  for (int mt = 0; mt < 4; ++mt) {
#pragma unroll
    for (int r = 0; r < 4; ++r) {
      const int rowl = mt * 16 + quad * 4 + r;
#pragma unroll
      for (int nt = 0; nt < 2; ++nt) {
        const int col = nb + nt * 16 + nlo;
        const int sw  = ((col >> 3) ^ (rowl & 15)) * 8 + (col & 7);
        At[rowl * HID + sw] = f2bf(acc[mt][nt][r]);
      }
    }
  }
  __syncthreads();

  // ---- int8 quantized store: per-row amax scale, 8 B/thread ----
#pragma unroll
  for (int i = 0; i < 4; ++i) {
    const int c   = tid + i * 256;
    const int row = c >> 4;
    const int c16 = c & 15;
    const int gr  = r0 + row;
    bf16x8 v = *(const bf16x8*)(At + row * HID + ((c16 ^ (row & 15)) * 8));
    float x[8];
    float m = 0.f;
#pragma unroll
    for (int j = 0; j < 8; ++j) {
      x[j] = bf2f(v[j]);
      m = fmaxf(m, __builtin_fabsf(x[j]));
    }
    // amax across the 16 lanes holding this row (consecutive lanes)
    m = fmaxf(m, __shfl_xor(m, 1));
    m = fmaxf(m, __shfl_xor(m, 2));
    m = fmaxf(m, __shfl_xor(m, 4));
    m = fmaxf(m, __shfl_xor(m, 8));
    const float inv = (m > 0.f) ? 127.f / m : 0.f;
    unsigned lo = 0, hi = 0;
#pragma unroll
    for (int j = 0; j < 4; ++j) {
      const int q = (int)rintf(x[j] * inv);
      lo |= ((unsigned)(q & 0xff)) << (8 * j);
    }
#pragma unroll
    for (int j = 0; j < 4; ++j) {
      const int q = (int)rintf(x[4 + j] * inv);
      hi |= ((unsigned)(q & 0xff)) << (8 * j);
    }
    if (gr < M) {
      *(uint2*)(Hq + (size_t)gr * HID + c16 * 8) = make_uint2(lo, hi);
      if (c16 == 0) S[gr] = m * (1.f / 127.f);
    }
  }
}

// ---------------- Phase 2: out[e] = W2 . relu(dq(Hqs[row]) + dq(Hqd[col]) + b1) + b2 ----
// int8 rows: 128 B gather per side + broadcast scalar scale (L2-resident).
__global__ __launch_bounds__(256, 8)
void edge_eval(const unsigned char* __restrict__ Hqs,
               const unsigned char* __restrict__ Hqd,
               const float* __restrict__ Ss, const float* __restrict__ Sd,
               const int* __restrict__ eidx,
               const float* __restrict__ b1, const float* __restrict__ W2,
               const float* __restrict__ b2,
               float* __restrict__ out, int E)
{
  const int tid = threadIdx.x;
  const int l16 = tid & 15;
  const int ebase = blockIdx.x * 64 + (tid >> 4) * 4;

  int rows[4], cols[4];
#pragma unroll
  for (int u = 0; u < 4; ++u) {
    const int e = ebase + u;
    const bool ok = e < E;
    rows[u] = ok ? eidx[e] : 0;
    cols[u] = ok ? eidx[E + e] : 0;
  }

  uint2 qs[4], qd[4];
  float ss[4], sd[4];
#pragma unroll
  for (int u = 0; u < 4; ++u)
    qs[u] = *(const uint2*)(Hqs + (size_t)rows[u] * HID + l16 * 8);
#pragma unroll
  for (int u = 0; u < 4; ++u)
    qd[u] = *(const uint2*)(Hqd + (size_t)cols[u] * HID + l16 * 8);
#pragma unroll
  for (int u = 0; u < 4; ++u) ss[u] = Ss[rows[u]];
#pragma unroll
  for (int u = 0; u < 4; ++u) sd[u] = Sd[cols[u]];

  float4 b1a = *(const float4*)(b1 + l16 * 8);
  float4 b1b = *(const float4*)(b1 + l16 * 8 + 4);
  float4 w2a = *(const float4*)(W2 + l16 * 8);
  float4 w2b = *(const float4*)(W2 + l16 * 8 + 4);
  const float b1v[8] = {b1a.x, b1a.y, b1a.z, b1a.w, b1b.x, b1b.y, b1b.z, b1b.w};
  const float w2v[8] = {w2a.x, w2a.y, w2a.z, w2a.w, w2b.x, w2b.y, w2b.z, w2b.w};
  const float bias2 = b2[0];

  float v[4];
#pragma unroll
  for (int u = 0; u < 4; ++u) {
    float s = 0.f;
#pragma unroll
    for (int j = 0; j < 8; ++j) {
      float x = fmaf(i8at(qs[u], j), ss[u], fmaf(i8at(qd[u], j), sd[u], b1v[j]));
      x = fmaxf(x, 0.f);
      s = fmaf(x, w2v[j], s);
    }
    s += __shfl_xor(s, 1);
    s += __shfl_xor(s, 2);
    s += __shfl_xor(s, 4);
    s += __shfl_xor(s, 8);
    v[u] = s;
  }
  if (l16 < 4) {
    const int e = ebase + l16;
    const float vo = (l16 == 0) ? v[0] : (l16 == 1) ? v[1] : (l16 == 2) ? v[2] : v[3];
    if (e < E) out[e] = vo + bias2;
  }
}

// ---------------- Fallback (ws too small): fused kernel, fp32 direct ----------------
__global__ __launch_bounds__(256, 4)
void edge_decoder_f32(const float* __restrict__ zsrc_f, const float* __restrict__ zdst_f,
                      const int* __restrict__ eidx,
                      const float* __restrict__ W1f,
                      const float* __restrict__ b1, const float* __restrict__ W2,
                      const float* __restrict__ b2,
                      float* __restrict__ out, int E)
{
  __shared__ unsigned short Zt[TILE_E * K256];
  __shared__ int   idxs[2 * TILE_E];
  __shared__ float part[4 * TILE_E];

  const int tid  = threadIdx.x;
  const int lane = tid & 63;
  const int nh   = tid >> 6;
  const int nlo  = lane & 15;
  const int quad = lane >> 4;
  const int e0   = blockIdx.x * TILE_E;

  if (tid < 2 * TILE_E) {
    const int ee = e0 + (tid & 63);
    idxs[tid] = (ee < E) ? eidx[(tid >> 6) * E + ee] : 0;
  }
  __syncthreads();

#pragma unroll
  for (int it = 0; it < 8; ++it) {
    const int c   = tid + it * 256;
    const int row = c >> 4;
    const int l16 = c & 15;
    const int e   = row >> 1;
    const int h   = row & 1;
    const int node = idxs[h * TILE_E + e];
    const int cs  = ((h << 4) | l16) ^ (e & 31);
    const float* p = (h ? zdst_f : zsrc_f) + (size_t)node * HID + l16 * 8;
    bf16x8 v = pack8(*(const float4*)p, *(const float4*)(p + 4));
    *(bf16x8*)(Zt + e * K256 + cs * 8) = v;
  }
  __syncthreads();

  bf16x8 w1f[2][8];
  const int nb = nh * 32;
#pragma unroll
  for (int nt = 0; nt < 2; ++nt) {
    const int n = nb + nt * 16 + nlo;
#pragma unroll
    for (int kt = 0; kt < 8; ++kt) {
      const float* p = W1f + (size_t)n * K256 + kt * 32 + quad * 8;
      w1f[nt][kt] = pack8(*(const float4*)p, *(const float4*)(p + 4));
    }
  }

  floatx4 acc[4][2];
#pragma unroll
  for (int mt = 0; mt < 4; ++mt)
#pragma unroll
    for (int nt = 0; nt < 2; ++nt)
      acc[mt][nt] = (floatx4){0.f, 0.f, 0.f, 0.f};

#pragma unroll
  for (int kt = 0; kt < 8; ++kt) {
    bf16x8 a[4];
#pragma unroll
    for (int mt = 0; mt < 4; ++mt) {
      const int m  = mt * 16 + nlo;
      const int cs = (kt * 4 + quad) ^ (m & 31);
      a[mt] = *(const bf16x8*)(Zt + m * K256 + cs * 8);
    }
#pragma unroll
    for (int mt = 0; mt < 4; ++mt)
#pragma unroll
      for (int nt = 0; nt < 2; ++nt)
        acc[mt][nt] = __builtin_amdgcn_mfma_f32_16x16x32_bf16(
            a[mt], w1f[nt][kt], acc[mt][nt], 0, 0, 0);
  }

  float b1v[2], w2v[2];
#pragma unroll
  for (int nt = 0; nt < 2; ++nt) {
    const int n = nb + nt * 16 + nlo;
    b1v[nt] = b1[n];
    w2v[nt] = W2[n];
  }
#pragma unroll
  for (int mt = 0; mt < 4; ++mt) {
#pragma unroll
    for (int r = 0; r < 4; ++r) {
      float v = 0.f;
#pragma unroll
      for (int nt = 0; nt < 2; ++nt) {
        float x = acc[mt][nt][r] + b1v[nt];
        x = fmaxf(x, 0.f);
        v = fmaf(x, w2v[nt], v);
      }
      v += __shfl_xor(v, 1);
      v += __shfl_xor(v, 2);
      v += __shfl_xor(v, 4);
      v += __shfl_xor(v, 8);
      if (nlo == 0)
        part[nh * TILE_E + mt * 16 + quad * 4 + r] = v;
    }
  }
  __syncthreads();
  if (tid < TILE_E && e0 + tid < E)
    out[e0 + tid] = part[tid] + part[TILE_E + tid] + part[2 * TILE_E + tid]
                  + part[3 * TILE_E + tid] + b2[0];
}

extern "C" void kernel_launch(void* const* d_in, const int* in_sizes, int n_in,
                              void* d_out, int out_size, void* d_ws, size_t ws_size,
                              hipStream_t stream) {
  const float* z_src = (const float*)d_in[0];
  const float* z_dst = (const float*)d_in[1];
  const int*   eidx  = (const int*)d_in[2];
  const float* W1    = (const float*)d_in[3];
  const float* b1    = (const float*)d_in[4];
  const float* W2    = (const float*)d_in[5];
  const float* b2    = (const float*)d_in[6];
  float* out = (float*)d_out;

  const int NH = in_sizes[0];        // 12,800,000 = M * 128
  const int M  = NH / HID;           // 100,000
  const int E  = in_sizes[2] / 2;    // 1,000,000

  const size_t rowBytes = (size_t)M * HID;                    // int8 per side
  const size_t need = rowBytes * 2 + 2 * (size_t)M * sizeof(float);
  if (ws_size >= need) {
    unsigned char* Hqs = (unsigned char*)d_ws;
    unsigned char* Hqd = Hqs + rowBytes;
    float* Ss = (float*)(Hqd + rowBytes);
    float* Sd = Ss + M;
    const int nMt = (M + TILE_M - 1) / TILE_M;   // 1563
    node_proj<<<dim3(nMt, 2), 256, 0, stream>>>(z_src, z_dst, W1, Hqs, Hqd, Ss, Sd, M);
    edge_eval<<<(E + 63) / 64, 256, 0, stream>>>(Hqs, Hqd, Ss, Sd, eidx, b1, W2, b2, out, E);
  } else {
    const int nblk = (E + TILE_E - 1) / TILE_E;
    edge_decoder_f32<<<nblk, 256, 0, stream>>>(z_src, z_dst, eidx, W1, b1, W2, b2, out, E);
  }
}

// Round 6
// 188.247 us; speedup vs baseline: 1.2189x; 1.0147x over previous
//
#include <hip/hip_runtime.h>
#include <hip/hip_bf16.h>

#define HID    128     // hidden width per half
#define K256   256
#define TILE_M 64      // rows per block
#define TILE_E 64

typedef __attribute__((ext_vector_type(8))) short bf16x8;
typedef __attribute__((ext_vector_type(4))) float floatx4;

__device__ __forceinline__ unsigned short f2bf(float f) {
  __hip_bfloat16 b = __float2bfloat16(f);
  return __builtin_bit_cast(unsigned short, b);
}
__device__ __forceinline__ float bf2f(short s) {
  union { unsigned u; float f; } v; v.u = ((unsigned)(unsigned short)s) << 16;
  return v.f;
}
__device__ __forceinline__ bf16x8 pack8(float4 a, float4 b) {
  bf16x8 r;
  r[0] = (short)f2bf(a.x); r[1] = (short)f2bf(a.y);
  r[2] = (short)f2bf(a.z); r[3] = (short)f2bf(a.w);
  r[4] = (short)f2bf(b.x); r[5] = (short)f2bf(b.y);
  r[6] = (short)f2bf(b.z); r[7] = (short)f2bf(b.w);
  return r;
}
__device__ __forceinline__ float i8at(uint2 q, int j) {
  unsigned w = (j < 4) ? q.x : q.y;
  return (float)((int)(signed char)(w >> (8 * (j & 3))));
}

// async 16B global->LDS DMA (lds dest: wave-uniform base + lane*16)
__device__ __forceinline__ void gload_lds16(const float* g, void* l) {
  __builtin_amdgcn_global_load_lds(
      (const __attribute__((address_space(1))) unsigned int*)g,
      (__attribute__((address_space(3))) unsigned int*)l, 16, 0, 0);
}

// ---------------- Phase 1: H = z * W1halfT  (M x 128, K=128) ----------------
// R4 was latency-bound with VGPR=56: compiler serialized the staged loads
// (load->wait->cvt->ds_write per iter => ~4 serial HBM latencies/block).
// Now: A-tile staged as FP32 via global_load_lds DMA (no data VGPRs, all 8
// chunks in flight), LDS linear, conflict-freedom via pre-swizzled GLOBAL
// source (16B-chunk c = p ^ (row&15), T21) + same XOR on ds_read_b128.
// fp32->bf16 conversion moves into the fragment-read phase (overlaps MFMA).
__global__ __launch_bounds__(256, 4)
void node_proj(const float* __restrict__ zs, const float* __restrict__ zd,
               const float* __restrict__ W1,
               unsigned char* __restrict__ Hqs, unsigned char* __restrict__ Hqd,
               float* __restrict__ Ss, float* __restrict__ Sd,
               int M)
{
  __shared__ float Af[TILE_M * HID];           // 32 KiB fp32 A-tile; reused as bf16 C-tile
  unsigned short* At = (unsigned short*)Af;    // alias for epilogue

  const int which = blockIdx.y;
  const float* __restrict__ z = which ? zd : zs;
  unsigned char* __restrict__ Hq = which ? Hqd : Hqs;
  float* __restrict__ S = which ? Sd : Ss;
  const int koff = which * HID;

  const int tid  = threadIdx.x;
  const int lane = tid & 63;
  const int w    = tid >> 6;
  const int nlo  = lane & 15;
  const int quad = lane >> 4;
  const int r0   = blockIdx.x * TILE_M;

  // ---- issue A-tile DMA first (8 x 16B per thread, back-to-back) ----
  // LDS linear: wave w, iter i covers bytes [w*8192 + i*1024, +1024).
  // lane l -> row = off/512, p = (off%512)/16 ; global chunk c = p ^ (row&15).
#pragma unroll
  for (int i = 0; i < 8; ++i) {
    const int off = w * 8192 + i * 1024 + lane * 16;   // byte offset in tile
    const int row = off >> 9;                          // /512 B per row
    const int p   = (off >> 4) & 31;                   // 16B chunk within row
    const int c   = p ^ (row & 15);
    int gr = r0 + row;
    gr = (gr < M) ? gr : (M - 1);                      // clamp; masked at store
    gload_lds16(z + (size_t)gr * HID + c * 4,
                (char*)Af + w * 8192 + i * 1024);
  }

  // ---- W1 B-fragments (L2-hot) overlap the DMA latency ----
  bf16x8 bfr[2][4];
  const int nb = w * 32;
#pragma unroll
  for (int nt = 0; nt < 2; ++nt) {
    const int n = nb + nt * 16 + nlo;
#pragma unroll
    for (int kt = 0; kt < 4; ++kt) {
      const float* p = W1 + (size_t)n * K256 + koff + kt * 32 + quad * 8;
      bfr[nt][kt] = pack8(*(const float4*)p, *(const float4*)(p + 4));
    }
  }
  __syncthreads();   // drains vmcnt (DMA) + lgkm

  // ---- MFMA: fragments read fp32 (2 x ds_read_b128, XOR-deswizzled) + cvt ----
  floatx4 acc[4][2];
#pragma unroll
  for (int mt = 0; mt < 4; ++mt)
#pragma unroll
    for (int nt = 0; nt < 2; ++nt)
      acc[mt][nt] = (floatx4){0.f, 0.f, 0.f, 0.f};

#pragma unroll
  for (int kt = 0; kt < 4; ++kt) {
    bf16x8 a[4];
#pragma unroll
    for (int mt = 0; mt < 4; ++mt) {
      const int m  = mt * 16 + nlo;
      const int c0 = kt * 8 + quad * 2;                // global 16B chunk (4 fp32)
      const int p0 = c0 ^ nlo;
      const int p1 = (c0 + 1) ^ nlo;
      float4 fa = *(const float4*)(Af + m * HID + p0 * 4);
      float4 fb = *(const float4*)(Af + m * HID + p1 * 4);
      a[mt] = pack8(fa, fb);
    }
#pragma unroll
    for (int mt = 0; mt < 4; ++mt)
#pragma unroll
      for (int nt = 0; nt < 2; ++nt)
        acc[mt][nt] = __builtin_amdgcn_mfma_f32_16x16x32_bf16(
            a[mt], bfr[nt][kt], acc[mt][nt], 0, 0, 0);
  }

  __syncthreads();                          // all A reads done -> reuse LDS for C
  // ---- C -> LDS (bf16, XOR-chunk swizzle) ----
#pragma unroll
  for (int mt = 0; mt < 4; ++mt) {
#pragma unroll
    for (int r = 0; r < 4; ++r) {
      const int rowl = mt * 16 + quad * 4 + r;
#pragma unroll
      for (int nt = 0; nt < 2; ++nt) {
        const int col = nb + nt * 16 + nlo;
        const int sw  = ((col >> 3) ^ (rowl & 15)) * 8 + (col & 7);
        At[rowl * HID + sw] = f2bf(acc[mt][nt][r]);
      }
    }
  }
  __syncthreads();

  // ---- int8 quantized store: per-row amax scale, 8 B/thread ----
#pragma unroll
  for (int i = 0; i < 4; ++i) {
    const int c   = tid + i * 256;
    const int row = c >> 4;
    const int c16 = c & 15;
    const int gr  = r0 + row;
    bf16x8 v = *(const bf16x8*)(At + row * HID + ((c16 ^ (row & 15)) * 8));
    float x[8];
    float m = 0.f;
#pragma unroll
    for (int j = 0; j < 8; ++j) {
      x[j] = bf2f(v[j]);
      m = fmaxf(m, __builtin_fabsf(x[j]));
    }
    m = fmaxf(m, __shfl_xor(m, 1));
    m = fmaxf(m, __shfl_xor(m, 2));
    m = fmaxf(m, __shfl_xor(m, 4));
    m = fmaxf(m, __shfl_xor(m, 8));
    const float inv = (m > 0.f) ? 127.f / m : 0.f;
    unsigned lo = 0, hi = 0;
#pragma unroll
    for (int j = 0; j < 4; ++j) {
      const int q = (int)rintf(x[j] * inv);
      lo |= ((unsigned)(q & 0xff)) << (8 * j);
    }
#pragma unroll
    for (int j = 0; j < 4; ++j) {
      const int q = (int)rintf(x[4 + j] * inv);
      hi |= ((unsigned)(q & 0xff)) << (8 * j);
    }
    if (gr < M) {
      *(uint2*)(Hq + (size_t)gr * HID + c16 * 8) = make_uint2(lo, hi);
      if (c16 == 0) S[gr] = m * (1.f / 127.f);
    }
  }
}

// ---------------- Phase 2: out[e] = W2 . relu(dq(Hqs[row]) + dq(Hqd[col]) + b1) + b2 ----
__global__ __launch_bounds__(256, 8)
void edge_eval(const unsigned char* __restrict__ Hqs,
               const unsigned char* __restrict__ Hqd,
               const float* __restrict__ Ss, const float* __restrict__ Sd,
               const int* __restrict__ eidx,
               const float* __restrict__ b1, const float* __restrict__ W2,
               const float* __restrict__ b2,
               float* __restrict__ out, int E)
{
  const int tid = threadIdx.x;
  const int l16 = tid & 15;
  const int ebase = blockIdx.x * 64 + (tid >> 4) * 4;

  int rows[4], cols[4];
#pragma unroll
  for (int u = 0; u < 4; ++u) {
    const int e = ebase + u;
    const bool ok = e < E;
    rows[u] = ok ? eidx[e] : 0;
    cols[u] = ok ? eidx[E + e] : 0;
  }

  uint2 qs[4], qd[4];
  float ss[4], sd[4];
#pragma unroll
  for (int u = 0; u < 4; ++u)
    qs[u] = *(const uint2*)(Hqs + (size_t)rows[u] * HID + l16 * 8);
#pragma unroll
  for (int u = 0; u < 4; ++u)
    qd[u] = *(const uint2*)(Hqd + (size_t)cols[u] * HID + l16 * 8);
#pragma unroll
  for (int u = 0; u < 4; ++u) ss[u] = Ss[rows[u]];
#pragma unroll
  for (int u = 0; u < 4; ++u) sd[u] = Sd[cols[u]];

  float4 b1a = *(const float4*)(b1 + l16 * 8);
  float4 b1b = *(const float4*)(b1 + l16 * 8 + 4);
  float4 w2a = *(const float4*)(W2 + l16 * 8);
  float4 w2b = *(const float4*)(W2 + l16 * 8 + 4);
  const float b1v[8] = {b1a.x, b1a.y, b1a.z, b1a.w, b1b.x, b1b.y, b1b.z, b1b.w};
  const float w2v[8] = {w2a.x, w2a.y, w2a.z, w2a.w, w2b.x, w2b.y, w2b.z, w2b.w};
  const float bias2 = b2[0];

  float v[4];
#pragma unroll
  for (int u = 0; u < 4; ++u) {
    float s = 0.f;
#pragma unroll
    for (int j = 0; j < 8; ++j) {
      float x = fmaf(i8at(qs[u], j), ss[u], fmaf(i8at(qd[u], j), sd[u], b1v[j]));
      x = fmaxf(x, 0.f);
      s = fmaf(x, w2v[j], s);
    }
    s += __shfl_xor(s, 1);
    s += __shfl_xor(s, 2);
    s += __shfl_xor(s, 4);
    s += __shfl_xor(s, 8);
    v[u] = s;
  }
  if (l16 < 4) {
    const int e = ebase + l16;
    const float vo = (l16 == 0) ? v[0] : (l16 == 1) ? v[1] : (l16 == 2) ? v[2] : v[3];
    if (e < E) out[e] = vo + bias2;
  }
}

// ---------------- Fallback (ws too small): fused kernel, fp32 direct ----------------
__global__ __launch_bounds__(256, 4)
void edge_decoder_f32(const float* __restrict__ zsrc_f, const float* __restrict__ zdst_f,
                      const int* __restrict__ eidx,
                      const float* __restrict__ W1f,
                      const float* __restrict__ b1, const float* __restrict__ W2,
                      const float* __restrict__ b2,
                      float* __restrict__ out, int E)
{
  __shared__ unsigned short Zt[TILE_E * K256];
  __shared__ int   idxs[2 * TILE_E];
  __shared__ float part[4 * TILE_E];

  const int tid  = threadIdx.x;
  const int lane = tid & 63;
  const int nh   = tid >> 6;
  const int nlo  = lane & 15;
  const int quad = lane >> 4;
  const int e0   = blockIdx.x * TILE_E;

  if (tid < 2 * TILE_E) {
    const int ee = e0 + (tid & 63);
    idxs[tid] = (ee < E) ? eidx[(tid >> 6) * E + ee] : 0;
  }
  __syncthreads();

#pragma unroll
  for (int it = 0; it < 8; ++it) {
    const int c   = tid + it * 256;
    const int row = c >> 4;
    const int l16 = c & 15;
    const int e   = row >> 1;
    const int h   = row & 1;
    const int node = idxs[h * TILE_E + e];
    const int cs  = ((h << 4) | l16) ^ (e & 31);
    const float* p = (h ? zdst_f : zsrc_f) + (size_t)node * HID + l16 * 8;
    bf16x8 v = pack8(*(const float4*)p, *(const float4*)(p + 4));
    *(bf16x8*)(Zt + e * K256 + cs * 8) = v;
  }
  __syncthreads();

  bf16x8 w1f[2][8];
  const int nb = nh * 32;
#pragma unroll
  for (int nt = 0; nt < 2; ++nt) {
    const int n = nb + nt * 16 + nlo;
#pragma unroll
    for (int kt = 0; kt < 8; ++kt) {
      const float* p = W1f + (size_t)n * K256 + kt * 32 + quad * 8;
      w1f[nt][kt] = pack8(*(const float4*)p, *(const float4*)(p + 4));
    }
  }

  floatx4 acc[4][2];
#pragma unroll
  for (int mt = 0; mt < 4; ++mt)
#pragma unroll
    for (int nt = 0; nt < 2; ++nt)
      acc[mt][nt] = (floatx4){0.f, 0.f, 0.f, 0.f};

#pragma unroll
  for (int kt = 0; kt < 8; ++kt) {
    bf16x8 a[4];
#pragma unroll
    for (int mt = 0; mt < 4; ++mt) {
      const int m  = mt * 16 + nlo;
      const int cs = (kt * 4 + quad) ^ (m & 31);
      a[mt] = *(const bf16x8*)(Zt + m * K256 + cs * 8);
    }
#pragma unroll
    for (int mt = 0; mt < 4; ++mt)
#pragma unroll
      for (int nt = 0; nt < 2; ++nt)
        acc[mt][nt] = __builtin_amdgcn_mfma_f32_16x16x32_bf16(
            a[mt], w1f[nt][kt], acc[mt][nt], 0, 0, 0);
  }

  float b1v[2], w2v[2];
#pragma unroll
  for (int nt = 0; nt < 2; ++nt) {
    const int n = nb + nt * 16 + nlo;
    b1v[nt] = b1[n];
    w2v[nt] = W2[n];
  }
#pragma unroll
  for (int mt = 0; mt < 4; ++mt) {
#pragma unroll
    for (int r = 0; r < 4; ++r) {
      float v = 0.f;
#pragma unroll
      for (int nt = 0; nt < 2; ++nt) {
        float x = acc[mt][nt][r] + b1v[nt];
        x = fmaxf(x, 0.f);
        v = fmaf(x, w2v[nt], v);
      }
      v += __shfl_xor(v, 1);
      v += __shfl_xor(v, 2);
      v += __shfl_xor(v, 4);
      v += __shfl_xor(v, 8);
      if (nlo == 0)
        part[nh * TILE_E + mt * 16 + quad * 4 + r] = v;
    }
  }
  __syncthreads();
  if (tid < TILE_E && e0 + tid < E)
    out[e0 + tid] = part[tid] + part[TILE_E + tid] + part[2 * TILE_E + tid]
                  + part[3 * TILE_E + tid] + b2[0];
}

extern "C" void kernel_launch(void* const* d_in, const int* in_sizes, int n_in,
                              void* d_out, int out_size, void* d_ws, size_t ws_size,
                              hipStream_t stream) {
  const float* z_src = (const float*)d_in[0];
  const float* z_dst = (const float*)d_in[1];
  const int*   eidx  = (const int*)d_in[2];
  const float* W1    = (const float*)d_in[3];
  const float* b1    = (const float*)d_in[4];
  const float* W2    = (const float*)d_in[5];
  const float* b2    = (const float*)d_in[6];
  float* out = (float*)d_out;

  const int NH = in_sizes[0];        // 12,800,000 = M * 128
  const int M  = NH / HID;           // 100,000
  const int E  = in_sizes[2] / 2;    // 1,000,000

  const size_t rowBytes = (size_t)M * HID;                    // int8 per side
  const size_t need = rowBytes * 2 + 2 * (size_t)M * sizeof(float);
  if (ws_size >= need) {
    unsigned char* Hqs = (unsigned char*)d_ws;
    unsigned char* Hqd = Hqs + rowBytes;
    float* Ss = (float*)(Hqd + rowBytes);
    float* Sd = Ss + M;
    const int nMt = (M + TILE_M - 1) / TILE_M;   // 1563
    node_proj<<<dim3(nMt, 2), 256, 0, stream>>>(z_src, z_dst, W1, Hqs, Hqd, Ss, Sd, M);
    edge_eval<<<(E + 63) / 64, 256, 0, stream>>>(Hqs, Hqd, Ss, Sd, eidx, b1, W2, b2, out, E);
  } else {
    const int nblk = (E + TILE_E - 1) / TILE_E;
    edge_decoder_f32<<<nblk, 256, 0, stream>>>(z_src, z_dst, eidx, W1, b1, W2, b2, out, E);
  }
}